// Round 13
// baseline (675.938 us; speedup 1.0000x reference)
//
#include <hip/hip_runtime.h>
#include <cstddef>
#include <cstdint>

// Problem constants: EMBED=1024, NUM_HEADS=16, GQA=4, KV_HEADS=4,
// HEAD_DIM=64, KV_EMBED=256, EPS=1e-3, B=2, T=1024.
#define TSEQ 1024

typedef __attribute__((ext_vector_type(8))) short short8;   // 8 bf16 = 4 VGPRs
typedef __attribute__((ext_vector_type(4))) float floatx4;  // MFMA acc

// Workspace layout (floats):
//  XQ : 2048 x 1024  (2M)
//  XK : 2048 x 256   (0.5M)
//  XVt: 2 x 256 x 1024 (0.5M)  -- V-projection TRANSPOSED: [b][h*64+c][j]
//  XO : 2048 x 1024  (2M)
//  P  : 32 x 1024x1024 (33.55M) -- q=1-p / phi in GROUP-DIAGONAL layout
static constexpr size_t OFF_XQ  = 0;
static constexpr size_t OFF_XK  = (size_t)2 * 1024 * 1024;
static constexpr size_t OFF_XVT = OFF_XK + (size_t)512 * 1024;
static constexpr size_t OFF_XO  = OFF_XVT + (size_t)512 * 1024;
static constexpr size_t OFF_P   = OFF_XO + (size_t)2 * 1024 * 1024;

// GROUP-DIAGONAL LAYOUT (R10): logical cell (r, c) lives at storage row
//   diagrow(r, c>>4) = (((r>>2) + (c>>4)) & 255)*4 + (r&3).
// R=4 rows per step: compute lane t owns cols [16t,16t+16), at step s
// handles row-group g = s - t (rows 4g..4g+3). One step = one contiguous
// 16KB slot (slot = s & 255), read as q and overwritten with phi in place.
// Valid steps: 0..318 (s=319 has no valid lane). Flushed phi cells for
// slot sf are exactly owner lanes T in [sf-255, sf]; other cells keep
// their q values (store predicate) for future consumption.
//
// R18 DIAGNOSIS (R17 autopsy): producer/consumer overlap worked (helpers
// off the critical path) but wave-0's LDS map ([k][j][t]) forced 128
// scalar b32 LDS ops/step (j-strided, unvectorizable) ~ 740cy issue ->
// 2200cy/step. Fix: transpose to [k][t][20-PAD]: wave-0 reads/writes its
// 16 values as 4x ds_read_b128 / 4x ds_write_b128 per k (32 LDS ops
// total). The 20-float pad (80B, 16B-aligned) gives lane-stride 20
// dwords: 8 lanes per 4-bank group, uniform 8 accesses/bank = the b128
// structural floor (a 16-float stride would pile 256 accesses into 8
// banks = 32-way). Helper publish/flush become single b128 per block at
// [16m+(l>>2)][4(l&3)] -- same (t,j) cell map on both sides.
// R16 (kept): raw barrier = lgkmcnt(0) + s_barrier ONLY (no vmcnt drain
// -- helper loads stay in flight); helpers do 8 VMEM/step each.
// R11 (kept): q-form recurrence, 2 fma/cell, no subs.

// ---------------------------------------------------------------------------
// fp32 -> bf16 hi/lo split (RNE). x ≈ hi + lo with residual ~2^-17 |x|.
// ---------------------------------------------------------------------------
__device__ __forceinline__ void cvt_hi_lo(float x, unsigned short& hi,
                                          unsigned short& lo) {
  unsigned u = __float_as_uint(x);
  unsigned rh = (u + 0x7FFFu + ((u >> 16) & 1u)) & 0xFFFF0000u;
  hi = (unsigned short)(rh >> 16);
  float xl = x - __uint_as_float(rh);
  unsigned ul = __float_as_uint(xl);
  unsigned rl = ul + 0x7FFFu + ((ul >> 16) & 1u);
  lo = (unsigned short)(rl >> 16);
}

__device__ __forceinline__ int diagrow(int r, int cblk) {
  return ((((r >> 2) + cblk) & 255) << 2) | (r & 3);
}

// ---------------------------------------------------------------------------
// Unified NT GEMM core, MFMA bf16x3 (R5-proven).
// ADIAG: A row index mapped through diagrow (reads group-diagonal matrix).
// CDIAG: C row index mapped through diagrow (writes group-diagonal matrix).
// EPI=2 writes q = sigmoid(-x) clipped (R11).
// ---------------------------------------------------------------------------
template <int EPI, int ADIAG, int CDIAG>
__device__ __forceinline__ void mfma_nt_core(
    const float* __restrict__ A, int lda,
    const float* __restrict__ B, int ldb,
    float* __restrict__ C, int ldc, int K,
    const float* __restrict__ bias)
{
  __shared__ __align__(16) unsigned short Ah[64][40];
  __shared__ __align__(16) unsigned short Al[64][40];
  __shared__ __align__(16) unsigned short Bh[64][40];
  __shared__ __align__(16) unsigned short Bl[64][40];

  const int bm = blockIdx.y << 6;
  const int bn = blockIdx.x << 6;
  const int tid  = threadIdx.x;
  const int lane = tid & 63;
  const int wave = tid >> 6;        // 0..3 -> row sub-tile
  const int m16  = lane & 15;
  const int quad = lane >> 4;

  const int srow = tid >> 2;        // staging: row 0..63
  const int skq  = (tid & 3) << 3;  // staging: k offset 0,8,16,24

  floatx4 acc[4];
#pragma unroll
  for (int c = 0; c < 4; ++c) acc[c] = (floatx4){0.f, 0.f, 0.f, 0.f};

  for (int k0 = 0; k0 < K; k0 += 32) {
    {
      const int kq = k0 + skq;
      int arow = bm + srow;
      if (ADIAG) arow = diagrow(arow, kq >> 4);
      const float* ap = A + (size_t)arow * lda + kq;
      const float* bp = B + (size_t)(bn + srow) * ldb + kq;
      float av[8] __attribute__((aligned(16)));
      float bv[8] __attribute__((aligned(16)));
      *(float4*)&av[0] = *(const float4*)(ap);
      *(float4*)&av[4] = *(const float4*)(ap + 4);
      *(float4*)&bv[0] = *(const float4*)(bp);
      *(float4*)&bv[4] = *(const float4*)(bp + 4);
      short8 vah, valo, vbh, vblo;
#pragma unroll
      for (int e = 0; e < 8; ++e) {
        unsigned short h, l;
        cvt_hi_lo(av[e], h, l);
        vah[e] = (short)h; valo[e] = (short)l;
        cvt_hi_lo(bv[e], h, l);
        vbh[e] = (short)h; vblo[e] = (short)l;
      }
      *(short8*)&Ah[srow][skq] = vah;
      *(short8*)&Al[srow][skq] = valo;
      *(short8*)&Bh[srow][skq] = vbh;
      *(short8*)&Bl[srow][skq] = vblo;
    }
    __syncthreads();

    const int arow = (wave << 4) + m16;
    const short8 a_h = *(const short8*)&Ah[arow][quad << 3];
    const short8 a_l = *(const short8*)&Al[arow][quad << 3];
#pragma unroll
    for (int c = 0; c < 4; ++c) {
      const int brow = (c << 4) + m16;
      const short8 b_h = *(const short8*)&Bh[brow][quad << 3];
      const short8 b_l = *(const short8*)&Bl[brow][quad << 3];
      acc[c] = __builtin_amdgcn_mfma_f32_16x16x32_bf16(a_h, b_h, acc[c], 0, 0, 0);
      acc[c] = __builtin_amdgcn_mfma_f32_16x16x32_bf16(a_h, b_l, acc[c], 0, 0, 0);
      acc[c] = __builtin_amdgcn_mfma_f32_16x16x32_bf16(a_l, b_h, acc[c], 0, 0, 0);
    }
    __syncthreads();
  }

#pragma unroll
  for (int c = 0; c < 4; ++c) {
#pragma unroll
    for (int r = 0; r < 4; ++r) {
      const int row = (wave << 4) + (quad << 2) + r;
      const int col = (c << 4) + m16;
      float v = acc[c][r];
      if (EPI == 0) { if (bias) v += bias[bn + col]; }
      if (EPI == 1) { v += bias[bm + row]; }
      if (EPI == 2) {
        // q = 1 - clip(sigmoid(v)) = clip(sigmoid(-v), 0.001, 0.999)
        v = 1.0f / (1.0f + expf(v));
        v = fminf(fmaxf(v, 0.001f), 0.999f);
      }
      int crow = bm + row;
      if (CDIAG) crow = diagrow(crow, (bn + col) >> 4);
      C[(size_t)crow * ldc + (bn + col)] = v;
    }
  }
}

__global__ __launch_bounds__(256) void gemm_nt_mfma_k(
    const float* __restrict__ A, int lda, const float* __restrict__ W, int ldw,
    const float* __restrict__ bias, float* __restrict__ C, int ldc, int K)
{
  mfma_nt_core<0, 0, 0>(A, lda, W, ldw, C, ldc, K, bias);
}

__global__ __launch_bounds__(256) void proj_vt_k(
    const float* __restrict__ vw, const float* __restrict__ value,
    const float* __restrict__ vb, float* __restrict__ XVt)
{
  const int b = blockIdx.z;
  mfma_nt_core<1, 0, 0>(vw, 1024, value + ((size_t)b << 20), 1024,
                        XVt + (size_t)b * 256 * 1024, 1024, 1024, vb);
}

// scores: writes q = 1-p in GROUP-DIAGONAL layout (CDIAG=1)
__global__ __launch_bounds__(256) void scores_mfma_k(
    const float* __restrict__ XQ, const float* __restrict__ XK,
    float* __restrict__ P)
{
  const int z = blockIdx.z;
  const int b = z >> 4;
  mfma_nt_core<2, 0, 1>(XQ + ((size_t)b << 20) + ((size_t)(z & 15) << 6), 1024,
                        XK + (size_t)b * TSEQ * 256 + ((size_t)(z & 3) << 6), 256,
                        P + ((size_t)z << 20), 1024, 64, nullptr);
}

// pv: reads phi (A matrix) from GROUP-DIAGONAL layout (ADIAG=1)
__global__ __launch_bounds__(256) void pv_mfma_k(
    const float* __restrict__ P, const float* __restrict__ XVt,
    float* __restrict__ XO)
{
  const int z = blockIdx.z;
  const int b = z >> 4;
  mfma_nt_core<0, 1, 0>(P + ((size_t)z << 20), 1024,
                        XVt + (size_t)b * 256 * 1024 + (size_t)(z & 3) * 64 * 1024, 1024,
                        XO + ((size_t)b << 20) + ((size_t)(z & 15) << 6), 1024,
                        1024, nullptr);
}

// ---------------------------------------------------------------------------
// Monotonic recurrence, producer/consumer v3 (R18). ONE 5-WAVE BLOCK per z.
// Wave 0 = exact R6 step body (q-form, shuffles, predicates); q source /
// phi sink are LDS, now as 4x b128 per k via the [k][t][20-pad] layout.
// Waves 1..4 (helper h owns in-slot row k=h-1): load slot s+2 (coalesced
// float4), publish slot s+1 to Qr[(s+1)&1], flush phi slot s-1 from
// Pr[(s-1)&1] to global (predicated to valid owner lanes).
// Raw barrier = lgkmcnt(0) + s_barrier (NO vmcnt drain).
// Cross-lane = __shfl only (DPP failed 3x on gfx950 -- permanently banned).
// ---------------------------------------------------------------------------
#define MONO_BAR() do {                                          \
    asm volatile("s_waitcnt lgkmcnt(0)" ::: "memory");           \
    __builtin_amdgcn_sched_barrier(0);                           \
    asm volatile("s_barrier" ::: "memory");                      \
    __builtin_amdgcn_sched_barrier(0);                           \
  } while (0)

#define LPAD 20   // 80B row pitch: 16B-aligned; lane-stride 20 dwords ->
                  // uniform 8 accesses/bank for b128 (structural floor)

__global__ __launch_bounds__(320, 1) void mono_rec_k(float* __restrict__ P)
{
  const int z = blockIdx.x;
  float* __restrict__ Pz = P + ((size_t)z << 20);
  const int tid = threadIdx.x;
  const int w   = tid >> 6;      // 0 = compute wave; 1..4 = helpers
  const int l   = tid & 63;      // lane

  // LDS: [ring2][k4][t64][LPAD] -- wave-0 does 4x b128 per k at [k][l].
  __shared__ __align__(16) float Qr[2][4][64][LPAD];   // q slots   (40 KB)
  __shared__ __align__(16) float Pr[2][4][64][LPAD];   // phi slots (40 KB)

  // ---- wave-0 persistent state ----
  float b[16];
  float phi15h[4], q15h[4];
#pragma unroll
  for (int c = 0; c < 16; ++c) b[c] = 0.0f;
#pragma unroll
  for (int k = 0; k < 4; ++k) { phi15h[k] = 0.0f; q15h[k] = 0.0f; }

  // ---- helper persistent buffers ----
  const int hk = (w > 0) ? (w - 1) : 0;
  float4 bufX[4], bufY[4];

  auto hload = [&](int slot, float4 (&buf)[4]) {
    const float* gp = Pz + ((size_t)(slot & 255) << 12) + (hk << 10) + (l << 2);
#pragma unroll
    for (int m = 0; m < 4; ++m) buf[m] = *(const float4*)(gp + (m << 8));
  };
  // publish q slot s1 into Qr[s1&1]; lane l block m = cols 256m+4l..+3
  // -> t = 16m + (l>>2), j0 = 4(l&3); one b128 per block.
  auto hpub = [&](int s1, const float4 (&buf)[4]) {
    const int rb = s1 & 1;
    const int j0 = (l & 3) << 2;
#pragma unroll
    for (int m = 0; m < 4; ++m) {
      const int tt = (m << 4) + (l >> 2);
      *(float4*)&Qr[rb][hk][tt][j0] = buf[m];
    }
  };
  // flush phi slot sf from Pr[sf&1] to global (predicated to owner lanes
  // T in [sf-255, sf]; other cells keep q -- in-place preserve).
  auto hflush = [&](int sf) {
    const int rb = sf & 1;
    const int j0 = (l & 3) << 2;
    float* sp = Pz + ((size_t)(sf & 255) << 12) + (hk << 10) + (l << 2);
#pragma unroll
    for (int m = 0; m < 4; ++m) {
      const int T = (m << 4) + (l >> 2);   // owning compute lane, 0..63
      if (T <= sf && T >= sf - 255)
        *(float4*)(sp + (m << 8)) = *(const float4*)&Pr[rb][hk][T][j0];
    }
  };

  // ---- wave-0 step: exact R6 body; q from Qr[s&1], phi to Pr[s&1] ----
  auto cstep = [&](int s) {
    const int rb = s & 1;
    float q[4][16];
#pragma unroll
    for (int k = 0; k < 4; ++k)
#pragma unroll
      for (int m = 0; m < 4; ++m)
        *(float4*)&q[k][4 * m] = *(const float4*)&Qr[rb][k][l][4 * m];

    float phiL[4], qL[4];
#pragma unroll
    for (int k = 0; k < 4; ++k) {
      phiL[k] = __shfl_up(phi15h[k], 1);
      qL[k]   = __shfl_up(q15h[k], 1);
    }

    const int g = s - l;
    if (g >= 0 && g < 256) {
#pragma unroll
      for (int k = 0; k < 4; ++k) {
        float phi[16] __attribute__((aligned(16)));
        if (g == 0 && k == 0) {
#pragma unroll
          for (int c = 0; c < 16; ++c) phi[c] = 0.0f;
          if (l == 0) phi[0] = 1.0f;
        } else {
          const float H0 = (l == 0) ? 0.0f : qL[k];
          float x = fmaf(H0, phiL[k], b[0]);
          phi[0] = x;
#pragma unroll
          for (int c = 1; c < 16; ++c) {
            x = fmaf(q[k][c - 1], x, b[c]);
            phi[c] = x;
          }
        }
#pragma unroll
        for (int c = 0; c < 16; ++c) b[c] = fmaf(-q[k][c], phi[c], phi[c]);
        q15h[k]   = q[k][15];
        phi15h[k] = phi[15];
#pragma unroll
        for (int m = 0; m < 4; ++m)
          *(float4*)&Pr[rb][k][l][4 * m] = *(const float4*)&phi[4 * m];
      }
    }
  };

  // ---- prologue: helpers stage slot 0 into ring 0, preload slot 1 ----
  if (w > 0) {
    hload(0, bufX);
    hload(1, bufY);
    hpub(0, bufX);      // compiler inserts counted vmcnt for bufX here
  }
  MONO_BAR();

  // ---- step 0: no flush ----
  if (w == 0) cstep(0);
  else { hload(2, bufX); hpub(1, bufY); }
  MONO_BAR();

  // ---- step 1: first flush (slot 0) ----
  if (w == 0) cstep(1);
  else { hload(3, bufY); hpub(2, bufX); hflush(0); }
  MONO_BAR();

  // ---- main loop: s = 2..319 (valid work ends at s=318) ----
  for (int s = 2; s < 320; s += 2) {
    if (w == 0) cstep(s);
    else { hload(s + 2, bufX); hpub(s + 1, bufY); hflush(s - 1); }
    MONO_BAR();
    if (w == 0) cstep(s + 1);
    else { hload(s + 3, bufY); hpub(s + 2, bufX); hflush(s); }
    MONO_BAR();
  }
  // flushes covered slots 0..318 = all valid steps (s=319 has no valid lane).
}

// ---------------------------------------------------------------------------
extern "C" void kernel_launch(void* const* d_in, const int* in_sizes, int n_in,
                              void* d_out, int out_size, void* d_ws, size_t ws_size,
                              hipStream_t stream)
{
  const float* query = (const float*)d_in[0];
  const float* key   = (const float*)d_in[1];
  const float* value = (const float*)d_in[2];
  const float* ipw   = (const float*)d_in[3];   // (1536,1024)
  const float* ipb   = (const float*)d_in[4];   // (1536,)
  const float* opw   = (const float*)d_in[5];   // (1024,1024)
  const float* opb   = (const float*)d_in[6];   // (1024,)
  float* out = (float*)d_out;
  float* ws  = (float*)d_ws;

  float* XQ  = ws + OFF_XQ;
  float* XK  = ws + OFF_XK;
  float* XVt = ws + OFF_XVT;
  float* XO  = ws + OFF_XO;
  float* P   = ws + OFF_P;

  // in-projections (MFMA bf16x3)
  gemm_nt_mfma_k<<<dim3(16, 32), 256, 0, stream>>>(
      query, 1024, ipw, 1024, ipb, XQ, 1024, 1024);
  gemm_nt_mfma_k<<<dim3(4, 32), 256, 0, stream>>>(
      key, 1024, ipw + (size_t)1024 * 1024, 1024, ipb + 1024, XK, 256, 1024);
  proj_vt_k<<<dim3(16, 4, 2), 256, 0, stream>>>(
      ipw + (size_t)1280 * 1024, value, ipb + 1280, XVt);

  // scores + sigmoid + clip -> q = 1-p (group-diagonal layout)
  scores_mfma_k<<<dim3(16, 16, 32), 256, 0, stream>>>(XQ, XK, P);

  // monotonic recurrence in place (producer/consumer v3: b128 LDS path)
  mono_rec_k<<<dim3(32), dim3(320), 0, stream>>>(P);

  // phi @ V -> XO (NT against transposed V; A read through diagonal map)
  pv_mfma_k<<<dim3(1, 16, 32), 256, 0, stream>>>(P, XVt, XO);

  // out-projection
  gemm_nt_mfma_k<<<dim3(16, 32), 256, 0, stream>>>(
      XO, 1024, opw, 1024, opb, out, 1024, 1024);
}

// Round 14
// 613.598 us; speedup vs baseline: 1.1016x; 1.1016x over previous
//
#include <hip/hip_runtime.h>
#include <cstddef>
#include <cstdint>

// Problem constants: EMBED=1024, NUM_HEADS=16, GQA=4, KV_HEADS=4,
// HEAD_DIM=64, KV_EMBED=256, EPS=1e-3, B=2, T=1024.
#define TSEQ 1024

typedef __attribute__((ext_vector_type(8))) short short8;   // 8 bf16 = 4 VGPRs
typedef __attribute__((ext_vector_type(4))) float floatx4;  // MFMA acc

// Workspace layout (floats):
//  XQ : 2048 x 1024  (2M)
//  XK : 2048 x 256   (0.5M)
//  XVt: 2 x 256 x 1024 (0.5M)  -- V-projection TRANSPOSED: [b][h*64+c][j]
//  XO : 2048 x 1024  (2M)
//  P  : 32 x 1024x1024 (33.55M) -- q=1-p / phi in GROUP-DIAGONAL layout
static constexpr size_t OFF_XQ  = 0;
static constexpr size_t OFF_XK  = (size_t)2 * 1024 * 1024;
static constexpr size_t OFF_XVT = OFF_XK + (size_t)512 * 1024;
static constexpr size_t OFF_XO  = OFF_XVT + (size_t)512 * 1024;
static constexpr size_t OFF_P   = OFF_XO + (size_t)2 * 1024 * 1024;

// GROUP-DIAGONAL LAYOUT (R10): logical cell (r, c) lives at storage row
//   diagrow(r, c>>4) = (((r>>2) + (c>>4)) & 255)*4 + (r&3).
// R=4 rows per step: lane t owns cols [16t,16t+16), at step s handles
// row-group g = s - t (rows 4g..4g+3). One step = one contiguous 16KB slot
// (slot = s & 255), read and overwritten in place. Wrap bijection: slot
// readers at step m+256 are lanes t>m; its writers at step m were lanes
// t<=m -- disjoint. Scores (CDIAG) writes and PV (ADIAG) reads through the
// same map; per-instruction coalescing preserved.
//
// R19: producer/consumer arc (R15-R18: 304/294/370 us) never beat the
// single-wave R11 mono (246.6 us) -- falsifier honored: mono reverted to
// R11 verbatim. GEMM side (~310us, ~62TF effective) gets a 128x64-tile
// core (mfma_nt_core2) for the four big GEMMs: 2x M per block halves
// staging-load + cvt_hi_lo + barrier cost per output (24 MFMA/wave/K-step
// vs 12). Arithmetic bit-identical to the proven 64x64 core.
// R11 (kept): q-form recurrence (scores stores q = 1-p), 2 fma/cell.

// ---------------------------------------------------------------------------
// fp32 -> bf16 hi/lo split (RNE). x ≈ hi + lo with residual ~2^-17 |x|.
// ---------------------------------------------------------------------------
__device__ __forceinline__ void cvt_hi_lo(float x, unsigned short& hi,
                                          unsigned short& lo) {
  unsigned u = __float_as_uint(x);
  unsigned rh = (u + 0x7FFFu + ((u >> 16) & 1u)) & 0xFFFF0000u;
  hi = (unsigned short)(rh >> 16);
  float xl = x - __uint_as_float(rh);
  unsigned ul = __float_as_uint(xl);
  unsigned rl = ul + 0x7FFFu + ((ul >> 16) & 1u);
  lo = (unsigned short)(rl >> 16);
}

__device__ __forceinline__ int diagrow(int r, int cblk) {
  return ((((r >> 2) + cblk) & 255) << 2) | (r & 3);
}

// ---------------------------------------------------------------------------
// Unified NT GEMM core, MFMA bf16x3, 64x64 tile (R5-proven).
// ADIAG: A row index mapped through diagrow. CDIAG: C row through diagrow.
// EPI=2 writes q = sigmoid(-x) clipped (R11).
// ---------------------------------------------------------------------------
template <int EPI, int ADIAG, int CDIAG>
__device__ __forceinline__ void mfma_nt_core(
    const float* __restrict__ A, int lda,
    const float* __restrict__ B, int ldb,
    float* __restrict__ C, int ldc, int K,
    const float* __restrict__ bias)
{
  __shared__ __align__(16) unsigned short Ah[64][40];
  __shared__ __align__(16) unsigned short Al[64][40];
  __shared__ __align__(16) unsigned short Bh[64][40];
  __shared__ __align__(16) unsigned short Bl[64][40];

  const int bm = blockIdx.y << 6;
  const int bn = blockIdx.x << 6;
  const int tid  = threadIdx.x;
  const int lane = tid & 63;
  const int wave = tid >> 6;        // 0..3 -> row sub-tile
  const int m16  = lane & 15;
  const int quad = lane >> 4;

  const int srow = tid >> 2;        // staging: row 0..63
  const int skq  = (tid & 3) << 3;  // staging: k offset 0,8,16,24

  floatx4 acc[4];
#pragma unroll
  for (int c = 0; c < 4; ++c) acc[c] = (floatx4){0.f, 0.f, 0.f, 0.f};

  for (int k0 = 0; k0 < K; k0 += 32) {
    {
      const int kq = k0 + skq;
      int arow = bm + srow;
      if (ADIAG) arow = diagrow(arow, kq >> 4);
      const float* ap = A + (size_t)arow * lda + kq;
      const float* bp = B + (size_t)(bn + srow) * ldb + kq;
      float av[8] __attribute__((aligned(16)));
      float bv[8] __attribute__((aligned(16)));
      *(float4*)&av[0] = *(const float4*)(ap);
      *(float4*)&av[4] = *(const float4*)(ap + 4);
      *(float4*)&bv[0] = *(const float4*)(bp);
      *(float4*)&bv[4] = *(const float4*)(bp + 4);
      short8 vah, valo, vbh, vblo;
#pragma unroll
      for (int e = 0; e < 8; ++e) {
        unsigned short h, l;
        cvt_hi_lo(av[e], h, l);
        vah[e] = (short)h; valo[e] = (short)l;
        cvt_hi_lo(bv[e], h, l);
        vbh[e] = (short)h; vblo[e] = (short)l;
      }
      *(short8*)&Ah[srow][skq] = vah;
      *(short8*)&Al[srow][skq] = valo;
      *(short8*)&Bh[srow][skq] = vbh;
      *(short8*)&Bl[srow][skq] = vblo;
    }
    __syncthreads();

    const int arow = (wave << 4) + m16;
    const short8 a_h = *(const short8*)&Ah[arow][quad << 3];
    const short8 a_l = *(const short8*)&Al[arow][quad << 3];
#pragma unroll
    for (int c = 0; c < 4; ++c) {
      const int brow = (c << 4) + m16;
      const short8 b_h = *(const short8*)&Bh[brow][quad << 3];
      const short8 b_l = *(const short8*)&Bl[brow][quad << 3];
      acc[c] = __builtin_amdgcn_mfma_f32_16x16x32_bf16(a_h, b_h, acc[c], 0, 0, 0);
      acc[c] = __builtin_amdgcn_mfma_f32_16x16x32_bf16(a_h, b_l, acc[c], 0, 0, 0);
      acc[c] = __builtin_amdgcn_mfma_f32_16x16x32_bf16(a_l, b_h, acc[c], 0, 0, 0);
    }
    __syncthreads();
  }

#pragma unroll
  for (int c = 0; c < 4; ++c) {
#pragma unroll
    for (int r = 0; r < 4; ++r) {
      const int row = (wave << 4) + (quad << 2) + r;
      const int col = (c << 4) + m16;
      float v = acc[c][r];
      if (EPI == 0) { if (bias) v += bias[bn + col]; }
      if (EPI == 1) { v += bias[bm + row]; }
      if (EPI == 2) {
        v = 1.0f / (1.0f + expf(v));
        v = fminf(fmaxf(v, 0.001f), 0.999f);
      }
      int crow = bm + row;
      if (CDIAG) crow = diagrow(crow, (bn + col) >> 4);
      C[(size_t)crow * ldc + (bn + col)] = v;
    }
  }
}

// ---------------------------------------------------------------------------
// 128x64-tile NT GEMM core (R19). 256 threads / 4 waves; wave w owns rows
// [32w, 32w+32) x all 64 cols: acc[2][4], 24 MFMAs per K-step per wave.
// A staged 16 floats/thread (row=tid>>1, khalf=(tid&1)*16 -- kq>>4 constant
// within each 16-float run, so ADIAG diagrow is per-thread-constant).
// B staged 8 floats/thread as in the 64x64 core. Same bf16x3 arithmetic.
// ---------------------------------------------------------------------------
template <int EPI, int ADIAG, int CDIAG>
__device__ __forceinline__ void mfma_nt_core2(
    const float* __restrict__ A, int lda,
    const float* __restrict__ B, int ldb,
    float* __restrict__ C, int ldc, int K,
    const float* __restrict__ bias)
{
  __shared__ __align__(16) unsigned short Ah[128][40];
  __shared__ __align__(16) unsigned short Al[128][40];
  __shared__ __align__(16) unsigned short Bh[64][40];
  __shared__ __align__(16) unsigned short Bl[64][40];

  const int bm = blockIdx.y << 7;   // 128-row tile
  const int bn = blockIdx.x << 6;
  const int tid  = threadIdx.x;
  const int lane = tid & 63;
  const int wave = tid >> 6;        // 0..3 -> 32-row sub-tile
  const int m16  = lane & 15;
  const int quad = lane >> 4;

  const int sArow = tid >> 1;          // A staging: row 0..127
  const int sAk   = (tid & 1) << 4;    // A staging: k offset 0 or 16
  const int sBrow = tid >> 2;          // B staging: row 0..63
  const int sBk   = (tid & 3) << 3;    // B staging: k offset 0,8,16,24

  floatx4 acc[2][4];
#pragma unroll
  for (int m = 0; m < 2; ++m)
#pragma unroll
    for (int n = 0; n < 4; ++n) acc[m][n] = (floatx4){0.f, 0.f, 0.f, 0.f};

  for (int k0 = 0; k0 < K; k0 += 32) {
    {
      const int kqA = k0 + sAk;
      int arow = bm + sArow;
      if (ADIAG) arow = diagrow(arow, kqA >> 4);   // constant over the 16 k's
      const float* ap = A + (size_t)arow * lda + kqA;
      float av[16] __attribute__((aligned(16)));
#pragma unroll
      for (int qd = 0; qd < 4; ++qd)
        *(float4*)&av[4 * qd] = *(const float4*)(ap + 4 * qd);
      short8 h0, h1, l0, l1;
#pragma unroll
      for (int e = 0; e < 8; ++e) {
        unsigned short h, l;
        cvt_hi_lo(av[e], h, l);
        h0[e] = (short)h; l0[e] = (short)l;
        cvt_hi_lo(av[8 + e], h, l);
        h1[e] = (short)h; l1[e] = (short)l;
      }
      *(short8*)&Ah[sArow][sAk]     = h0;
      *(short8*)&Ah[sArow][sAk + 8] = h1;
      *(short8*)&Al[sArow][sAk]     = l0;
      *(short8*)&Al[sArow][sAk + 8] = l1;

      const float* bp = B + (size_t)(bn + sBrow) * ldb + (k0 + sBk);
      float bv[8] __attribute__((aligned(16)));
      *(float4*)&bv[0] = *(const float4*)(bp);
      *(float4*)&bv[4] = *(const float4*)(bp + 4);
      short8 bh, bl;
#pragma unroll
      for (int e = 0; e < 8; ++e) {
        unsigned short h, l;
        cvt_hi_lo(bv[e], h, l);
        bh[e] = (short)h; bl[e] = (short)l;
      }
      *(short8*)&Bh[sBrow][sBk] = bh;
      *(short8*)&Bl[sBrow][sBk] = bl;
    }
    __syncthreads();

    short8 a_h[2], a_l[2];
#pragma unroll
    for (int m = 0; m < 2; ++m) {
      const int ar = (wave << 5) + (m << 4) + m16;
      a_h[m] = *(const short8*)&Ah[ar][quad << 3];
      a_l[m] = *(const short8*)&Al[ar][quad << 3];
    }
#pragma unroll
    for (int n = 0; n < 4; ++n) {
      const int brow = (n << 4) + m16;
      const short8 b_h = *(const short8*)&Bh[brow][quad << 3];
      const short8 b_l = *(const short8*)&Bl[brow][quad << 3];
#pragma unroll
      for (int m = 0; m < 2; ++m) {
        acc[m][n] = __builtin_amdgcn_mfma_f32_16x16x32_bf16(a_h[m], b_h, acc[m][n], 0, 0, 0);
        acc[m][n] = __builtin_amdgcn_mfma_f32_16x16x32_bf16(a_h[m], b_l, acc[m][n], 0, 0, 0);
        acc[m][n] = __builtin_amdgcn_mfma_f32_16x16x32_bf16(a_l[m], b_h, acc[m][n], 0, 0, 0);
      }
    }
    __syncthreads();
  }

#pragma unroll
  for (int m = 0; m < 2; ++m)
#pragma unroll
    for (int n = 0; n < 4; ++n)
#pragma unroll
      for (int r = 0; r < 4; ++r) {
        const int row = (wave << 5) + (m << 4) + (quad << 2) + r;
        const int col = (n << 4) + m16;
        float v = acc[m][n][r];
        if (EPI == 0) { if (bias) v += bias[bn + col]; }
        if (EPI == 2) {
          v = 1.0f / (1.0f + expf(v));
          v = fminf(fmaxf(v, 0.001f), 0.999f);
        }
        int crow = bm + row;
        if (CDIAG) crow = diagrow(crow, (bn + col) >> 4);
        C[(size_t)crow * ldc + (bn + col)] = v;
      }
}

__global__ __launch_bounds__(256) void gemm_nt_mfma_k(
    const float* __restrict__ A, int lda, const float* __restrict__ W, int ldw,
    const float* __restrict__ bias, float* __restrict__ C, int ldc, int K)
{
  mfma_nt_core<0, 0, 0>(A, lda, W, ldw, C, ldc, K, bias);
}

__global__ __launch_bounds__(256) void gemm_nt_mfma2_k(
    const float* __restrict__ A, int lda, const float* __restrict__ W, int ldw,
    const float* __restrict__ bias, float* __restrict__ C, int ldc, int K)
{
  mfma_nt_core2<0, 0, 0>(A, lda, W, ldw, C, ldc, K, bias);
}

__global__ __launch_bounds__(256) void proj_vt_k(
    const float* __restrict__ vw, const float* __restrict__ value,
    const float* __restrict__ vb, float* __restrict__ XVt)
{
  const int b = blockIdx.z;
  mfma_nt_core<1, 0, 0>(vw, 1024, value + ((size_t)b << 20), 1024,
                        XVt + (size_t)b * 256 * 1024, 1024, 1024, vb);
}

// scores: writes q = 1-p in GROUP-DIAGONAL layout (CDIAG=1), 128x64 tiles
__global__ __launch_bounds__(256) void scores_mfma2_k(
    const float* __restrict__ XQ, const float* __restrict__ XK,
    float* __restrict__ P)
{
  const int z = blockIdx.z;
  const int b = z >> 4;
  mfma_nt_core2<2, 0, 1>(XQ + ((size_t)b << 20) + ((size_t)(z & 15) << 6), 1024,
                         XK + (size_t)b * TSEQ * 256 + ((size_t)(z & 3) << 6), 256,
                         P + ((size_t)z << 20), 1024, 64, nullptr);
}

// pv: reads phi (A) from GROUP-DIAGONAL layout (ADIAG=1), 128x64 tiles
__global__ __launch_bounds__(256) void pv_mfma2_k(
    const float* __restrict__ P, const float* __restrict__ XVt,
    float* __restrict__ XO)
{
  const int z = blockIdx.z;
  const int b = z >> 4;
  mfma_nt_core2<0, 1, 0>(P + ((size_t)z << 20), 1024,
                         XVt + (size_t)b * 256 * 1024 + (size_t)(z & 3) * 64 * 1024, 1024,
                         XO + ((size_t)b << 20) + ((size_t)(z & 15) << 6), 1024,
                         1024, nullptr);
}

// ---------------------------------------------------------------------------
// Monotonic recurrence, 4-ROW diagonal wavefront in q-form (R11 verbatim --
// the session-best 246.6us version). ONE WAVE per z. Lane t owns cols
// [16t,16t+16); at step s handles row-group g = s - t (rows 4g..4g+3):
//   phi[r,c] = b[c] + q[r,c-1]*phi[r,c-1]        (1 fma)
//   b[c]     = fma(-q[r,c], phi[r,c], phi[r,c])  (= phi*p, 1 fma)
// Cross-lane: ONE batch of 8 __shfl_up(.,1) per step (phi15/q15 x 4 rows).
// q for step s+1 prefetched into registers (ping-pong pA/pB).
// Cross-lane = __shfl only (DPP failed 3x on gfx950 -- permanently banned).
// ---------------------------------------------------------------------------
__global__ __launch_bounds__(64) void mono_rec_k(float* __restrict__ P)
{
  const int z = blockIdx.x;
  float* __restrict__ Pz = P + ((size_t)z << 20);
  const int t = threadIdx.x;     // lane 0..63
  const int col0 = t << 4;       // first owned column

  float b[16];                   // carry: b[c] = phi[r-1,c] * p[r-1,c]
#pragma unroll
  for (int c = 0; c < 16; ++c) b[c] = 0.0f;
  float phi15h[4], q15h[4];      // col-15 values of the 4 rows, for lane t+1
#pragma unroll
  for (int k = 0; k < 4; ++k) { phi15h[k] = 0.0f; q15h[k] = 0.0f; }

  float pA[4][16], pB[4][16];    // q ping-pong (4 rows x 16 cols)

  // prologue: load slot 0 into pA
#pragma unroll
  for (int k = 0; k < 4; ++k) {
    const float* lp = Pz + (k << 10) + col0;
#pragma unroll
    for (int q = 0; q < 4; ++q)
      *(float4*)&pA[k][4 * q] = *(const float4*)(lp + 4 * q);
  }

  auto step = [&](int s, float (&pcur)[4][16], float (&pnext)[4][16]) {
    // boundary batch from lane t-1 first (latency overlaps prefetch issue).
    // Unconditional so source lanes are active in the shuffle.
    float phiL[4], qL[4];
#pragma unroll
    for (int k = 0; k < 4; ++k) {
      phiL[k] = __shfl_up(phi15h[k], 1);
      qL[k]   = __shfl_up(q15h[k], 1);
    }

    // prefetch next step's slot (never aliases in-flight stores: slots
    // s-1, s vs (s+1)&255 are distinct; wrap-overlap lanes are invalid)
    {
      const float* np = Pz + ((size_t)((s + 1) & 255) << 12) + col0;
#pragma unroll
      for (int k = 0; k < 4; ++k)
#pragma unroll
        for (int q = 0; q < 4; ++q)
          *(float4*)&pnext[k][4 * q] = *(const float4*)(np + (k << 10) + 4 * q);
    }

    const int g = s - t;
    if (g >= 0 && g < 256) {
      float* sp = Pz + ((size_t)(s & 255) << 12) + col0;
      float phi[16];
#pragma unroll
      for (int k = 0; k < 4; ++k) {
        const float* qk = pcur[k];
        if (g == 0 && k == 0) {
          // row 0: phi = onehot(col 0)
#pragma unroll
          for (int c = 0; c < 16; ++c) phi[c] = 0.0f;
          if (t == 0) phi[0] = 1.0f;
        } else {
          const float H0 = (t == 0) ? 0.0f : qL[k];
          float x = fmaf(H0, phiL[k], b[0]);
          phi[0] = x;
#pragma unroll
          for (int c = 1; c < 16; ++c) {
            x = fmaf(qk[c - 1], x, b[c]);
            phi[c] = x;
          }
        }
        // carry for next row (b = phi*p = phi - q*phi) + neighbor holds
#pragma unroll
        for (int c = 0; c < 16; ++c) b[c] = fmaf(-qk[c], phi[c], phi[c]);
        q15h[k]   = qk[15];
        phi15h[k] = phi[15];
        // write phi over q's cells (in-place, coalesced)
#pragma unroll
        for (int q = 0; q < 4; ++q)
          *(float4*)(sp + (k << 10) + 4 * q) = *(float4*)&phi[4 * q];
      }
    }
  };

  for (int s0 = 0; s0 < 320; s0 += 2) {
    step(s0, pA, pB);
    step(s0 + 1, pB, pA);
  }
}

// ---------------------------------------------------------------------------
extern "C" void kernel_launch(void* const* d_in, const int* in_sizes, int n_in,
                              void* d_out, int out_size, void* d_ws, size_t ws_size,
                              hipStream_t stream)
{
  const float* query = (const float*)d_in[0];
  const float* key   = (const float*)d_in[1];
  const float* value = (const float*)d_in[2];
  const float* ipw   = (const float*)d_in[3];   // (1536,1024)
  const float* ipb   = (const float*)d_in[4];   // (1536,)
  const float* opw   = (const float*)d_in[5];   // (1024,1024)
  const float* opb   = (const float*)d_in[6];   // (1024,)
  float* out = (float*)d_out;
  float* ws  = (float*)d_ws;

  float* XQ  = ws + OFF_XQ;
  float* XK  = ws + OFF_XK;
  float* XVt = ws + OFF_XVT;
  float* XO  = ws + OFF_XO;
  float* P   = ws + OFF_P;

  // in-projections (MFMA bf16x3); XQ uses the 128x64-tile core
  gemm_nt_mfma2_k<<<dim3(16, 16), 256, 0, stream>>>(
      query, 1024, ipw, 1024, ipb, XQ, 1024, 1024);
  gemm_nt_mfma_k<<<dim3(4, 32), 256, 0, stream>>>(
      key, 1024, ipw + (size_t)1024 * 1024, 1024, ipb + 1024, XK, 256, 1024);
  proj_vt_k<<<dim3(16, 4, 2), 256, 0, stream>>>(
      ipw + (size_t)1280 * 1024, value, ipb + 1280, XVt);

  // scores + sigmoid + clip -> q = 1-p (group-diagonal layout), 128x64
  scores_mfma2_k<<<dim3(16, 8, 32), 256, 0, stream>>>(XQ, XK, P);

  // monotonic recurrence in place (R11 single-wave, session best)
  mono_rec_k<<<dim3(32), dim3(64), 0, stream>>>(P);

  // phi @ V -> XO (NT against transposed V; A read through diagonal map)
  pv_mfma2_k<<<dim3(1, 8, 32), 256, 0, stream>>>(P, XVt, XO);

  // out-projection, 128x64
  gemm_nt_mfma2_k<<<dim3(16, 16), 256, 0, stream>>>(
      XO, 1024, opw, 1024, opb, out, 1024, 1024);
}

// Round 15
// 485.850 us; speedup vs baseline: 1.3912x; 1.2629x over previous
//
#include <hip/hip_runtime.h>
#include <cstddef>
#include <cstdint>

// Problem constants: EMBED=1024, NUM_HEADS=16, GQA=4, KV_HEADS=4,
// HEAD_DIM=64, KV_EMBED=256, EPS=1e-3, B=2, T=1024.
#define TSEQ 1024

typedef __attribute__((ext_vector_type(8))) short short8;   // 8 bf16 = 4 VGPRs
typedef __attribute__((ext_vector_type(4))) float floatx4;  // MFMA acc

// Workspace layout (floats):
//  XQ : 2048 x 1024  (2M)
//  XK : 2048 x 256   (0.5M)
//  XVt: 2 x 256 x 1024 (0.5M)  -- V-projection TRANSPOSED: [b][h*64+c][j]
//  XO : 2048 x 1024  (2M)
//  P  : 32 x 1024x1024 (33.55M) -- q=1-p / phi in GROUP-DIAGONAL layout
static constexpr size_t OFF_XQ  = 0;
static constexpr size_t OFF_XK  = (size_t)2 * 1024 * 1024;
static constexpr size_t OFF_XVT = OFF_XK + (size_t)512 * 1024;
static constexpr size_t OFF_XO  = OFF_XVT + (size_t)512 * 1024;
static constexpr size_t OFF_P   = OFF_XO + (size_t)2 * 1024 * 1024;

// GROUP-DIAGONAL LAYOUT (R10): logical cell (r, c) lives at storage row
//   diagrow(r, c>>4) = (((r>>2) + (c>>4)) & 255)*4 + (r&3).
// R=4 rows per step: lane t owns cols [16t,16t+16), at step s handles
// row-group g = s - t (rows 4g..4g+3). One step = one contiguous 16KB slot
// (slot = s & 255), read and overwritten in place. Wrap bijection: slot
// readers at step m+256 are lanes t>m; its writers at step m were lanes
// t<=m -- disjoint. Scores (CDIAG) writes and PV (ADIAG) reads through the
// same map; per-instruction coalescing preserved.
//
// R20: R19's 128x64 tiles REGRESSED the GEMM side (309 -> 367us): halving
// block counts to 1 block/CU removed the inter-block overlap hiding the
// per-K-step staging latency (these GEMMs are latency/occupancy-bound,
// not issue-bound -- chip-wide cvt arithmetic is only ~6us). Reverted to
// the R6-proven 64x64 core everywhere. New: (a) the three in-projections
// fused into ONE 768-block launch (XK/XVt were two half-empty 128-block
// rounds + two launch gaps); LDS hoisted to kernel scope so the three
// inlined core instances share one 20KB allocation. (b) __expf in the
// sigmoid epilogue (v_exp_f32 fast path; ~1ulp through a clipped sigmoid).
// R11 (kept): q-form recurrence (scores stores q = 1-p), 2 fma/cell;
// mono_rec_k is the R11/R6 single-wave version verbatim (246us measured,
// re-confirmed R14; the 5-wave producer/consumer arc R15-R18 never beat it).

// ---------------------------------------------------------------------------
// fp32 -> bf16 hi/lo split (RNE). x ≈ hi + lo with residual ~2^-17 |x|.
// ---------------------------------------------------------------------------
__device__ __forceinline__ void cvt_hi_lo(float x, unsigned short& hi,
                                          unsigned short& lo) {
  unsigned u = __float_as_uint(x);
  unsigned rh = (u + 0x7FFFu + ((u >> 16) & 1u)) & 0xFFFF0000u;
  hi = (unsigned short)(rh >> 16);
  float xl = x - __uint_as_float(rh);
  unsigned ul = __float_as_uint(xl);
  unsigned rl = ul + 0x7FFFu + ((ul >> 16) & 1u);
  lo = (unsigned short)(rl >> 16);
}

__device__ __forceinline__ int diagrow(int r, int cblk) {
  return ((((r >> 2) + cblk) & 255) << 2) | (r & 3);
}

typedef unsigned short lds_tile_t[40];

// ---------------------------------------------------------------------------
// Unified NT GEMM core, MFMA bf16x3, 64x64 tile (R5-proven; body unchanged
// from the 555.5us R6 version except bm/bn and LDS arrays are parameters).
// ADIAG: A row index mapped through diagrow. CDIAG: C row through diagrow.
// EPI=2 writes q = sigmoid(-x) clipped (R11), via __expf (R20).
// ---------------------------------------------------------------------------
template <int EPI, int ADIAG, int CDIAG>
__device__ __forceinline__ void mfma_nt_core(
    const float* __restrict__ A, int lda,
    const float* __restrict__ B, int ldb,
    float* __restrict__ C, int ldc, int K,
    const float* __restrict__ bias,
    int bm, int bn,
    lds_tile_t* __restrict__ Ah, lds_tile_t* __restrict__ Al,
    lds_tile_t* __restrict__ Bh, lds_tile_t* __restrict__ Bl)
{
  const int tid  = threadIdx.x;
  const int lane = tid & 63;
  const int wave = tid >> 6;        // 0..3 -> row sub-tile
  const int m16  = lane & 15;
  const int quad = lane >> 4;

  const int srow = tid >> 2;        // staging: row 0..63
  const int skq  = (tid & 3) << 3;  // staging: k offset 0,8,16,24

  floatx4 acc[4];
#pragma unroll
  for (int c = 0; c < 4; ++c) acc[c] = (floatx4){0.f, 0.f, 0.f, 0.f};

  for (int k0 = 0; k0 < K; k0 += 32) {
    {
      const int kq = k0 + skq;
      int arow = bm + srow;
      if (ADIAG) arow = diagrow(arow, kq >> 4);
      const float* ap = A + (size_t)arow * lda + kq;
      const float* bp = B + (size_t)(bn + srow) * ldb + kq;
      float av[8] __attribute__((aligned(16)));
      float bv[8] __attribute__((aligned(16)));
      *(float4*)&av[0] = *(const float4*)(ap);
      *(float4*)&av[4] = *(const float4*)(ap + 4);
      *(float4*)&bv[0] = *(const float4*)(bp);
      *(float4*)&bv[4] = *(const float4*)(bp + 4);
      short8 vah, valo, vbh, vblo;
#pragma unroll
      for (int e = 0; e < 8; ++e) {
        unsigned short h, l;
        cvt_hi_lo(av[e], h, l);
        vah[e] = (short)h; valo[e] = (short)l;
        cvt_hi_lo(bv[e], h, l);
        vbh[e] = (short)h; vblo[e] = (short)l;
      }
      *(short8*)&Ah[srow][skq] = vah;
      *(short8*)&Al[srow][skq] = valo;
      *(short8*)&Bh[srow][skq] = vbh;
      *(short8*)&Bl[srow][skq] = vblo;
    }
    __syncthreads();

    const int arow = (wave << 4) + m16;
    const short8 a_h = *(const short8*)&Ah[arow][quad << 3];
    const short8 a_l = *(const short8*)&Al[arow][quad << 3];
#pragma unroll
    for (int c = 0; c < 4; ++c) {
      const int brow = (c << 4) + m16;
      const short8 b_h = *(const short8*)&Bh[brow][quad << 3];
      const short8 b_l = *(const short8*)&Bl[brow][quad << 3];
      acc[c] = __builtin_amdgcn_mfma_f32_16x16x32_bf16(a_h, b_h, acc[c], 0, 0, 0);
      acc[c] = __builtin_amdgcn_mfma_f32_16x16x32_bf16(a_h, b_l, acc[c], 0, 0, 0);
      acc[c] = __builtin_amdgcn_mfma_f32_16x16x32_bf16(a_l, b_h, acc[c], 0, 0, 0);
    }
    __syncthreads();
  }

#pragma unroll
  for (int c = 0; c < 4; ++c) {
#pragma unroll
    for (int r = 0; r < 4; ++r) {
      const int row = (wave << 4) + (quad << 2) + r;
      const int col = (c << 4) + m16;
      float v = acc[c][r];
      if (EPI == 0) { if (bias) v += bias[bn + col]; }
      if (EPI == 1) { v += bias[bm + row]; }
      if (EPI == 2) {
        // q = 1 - clip(sigmoid(v)) = clip(sigmoid(-v), 0.001, 0.999)
        v = 1.0f / (1.0f + __expf(v));
        v = fminf(fmaxf(v, 0.001f), 0.999f);
      }
      int crow = bm + row;
      if (CDIAG) crow = diagrow(crow, (bn + col) >> 4);
      C[(size_t)crow * ldc + (bn + col)] = v;
    }
  }
}

#define DECL_GEMM_SMEM                                          \
  __shared__ __align__(16) unsigned short Ah[64][40];           \
  __shared__ __align__(16) unsigned short Al[64][40];           \
  __shared__ __align__(16) unsigned short Bh[64][40];           \
  __shared__ __align__(16) unsigned short Bl[64][40];

// ---------------------------------------------------------------------------
// Fused in-projections (R20): one 768-block launch.
//   blocks [0,512):   XQ  = query @ qw^T + qb      (grid was 16 x 32)
//   blocks [512,640): XK  = key @ kw^T + kb        (grid was 4 x 32)
//   blocks [640,768): XVt = (vw @ value^T) + vb    (grid was 16 x 4 x 2)
// Block-uniform dispatch; single shared 20KB LDS tile set.
// ---------------------------------------------------------------------------
__global__ __launch_bounds__(256) void inproj_k(
    const float* __restrict__ query, const float* __restrict__ key,
    const float* __restrict__ value, const float* __restrict__ ipw,
    const float* __restrict__ ipb,
    float* __restrict__ XQ, float* __restrict__ XK, float* __restrict__ XVt)
{
  DECL_GEMM_SMEM
  const int id = blockIdx.x;
  if (id < 512) {
    // XQ: bn = (id&15)*64, bm = (id>>4)*64
    mfma_nt_core<0, 0, 0>(query, 1024, ipw, 1024, XQ, 1024, 1024, ipb,
                          (id >> 4) << 6, (id & 15) << 6, Ah, Al, Bh, Bl);
  } else if (id < 640) {
    const int j = id - 512;   // bn = (j&3)*64, bm = (j>>2)*64
    mfma_nt_core<0, 0, 0>(key, 1024, ipw + ((size_t)1 << 20), 1024,
                          XK, 256, 1024, ipb + 1024,
                          (j >> 2) << 6, (j & 3) << 6, Ah, Al, Bh, Bl);
  } else {
    const int j = id - 640;   // bx = j&15, by = (j>>4)&3, b = j>>6
    const int b = j >> 6;
    mfma_nt_core<1, 0, 0>(ipw + (size_t)1280 * 1024, 1024,
                          value + ((size_t)b << 20), 1024,
                          XVt + (size_t)b * 256 * 1024, 1024, 1024,
                          ipb + 1280,
                          ((j >> 4) & 3) << 6, (j & 15) << 6, Ah, Al, Bh, Bl);
  }
}

// out-projection (and generic NT GEMM), 64x64 tiles
__global__ __launch_bounds__(256) void gemm_nt_mfma_k(
    const float* __restrict__ A, int lda, const float* __restrict__ W, int ldw,
    const float* __restrict__ bias, float* __restrict__ C, int ldc, int K)
{
  DECL_GEMM_SMEM
  mfma_nt_core<0, 0, 0>(A, lda, W, ldw, C, ldc, K, bias,
                        blockIdx.y << 6, blockIdx.x << 6, Ah, Al, Bh, Bl);
}

// scores: writes q = 1-p in GROUP-DIAGONAL layout (CDIAG=1)
__global__ __launch_bounds__(256) void scores_mfma_k(
    const float* __restrict__ XQ, const float* __restrict__ XK,
    float* __restrict__ P)
{
  DECL_GEMM_SMEM
  const int z = blockIdx.z;
  const int b = z >> 4;
  mfma_nt_core<2, 0, 1>(XQ + ((size_t)b << 20) + ((size_t)(z & 15) << 6), 1024,
                        XK + (size_t)b * TSEQ * 256 + ((size_t)(z & 3) << 6), 256,
                        P + ((size_t)z << 20), 1024, 64, nullptr,
                        blockIdx.y << 6, blockIdx.x << 6, Ah, Al, Bh, Bl);
}

// pv: reads phi (A) from GROUP-DIAGONAL layout (ADIAG=1)
__global__ __launch_bounds__(256) void pv_mfma_k(
    const float* __restrict__ P, const float* __restrict__ XVt,
    float* __restrict__ XO)
{
  DECL_GEMM_SMEM
  const int z = blockIdx.z;
  const int b = z >> 4;
  mfma_nt_core<0, 1, 0>(P + ((size_t)z << 20), 1024,
                        XVt + (size_t)b * 256 * 1024 + (size_t)(z & 3) * 64 * 1024, 1024,
                        XO + ((size_t)b << 20) + ((size_t)(z & 15) << 6), 1024,
                        1024, nullptr,
                        blockIdx.y << 6, blockIdx.x << 6, Ah, Al, Bh, Bl);
}

// ---------------------------------------------------------------------------
// Monotonic recurrence, 4-ROW diagonal wavefront in q-form (R11 verbatim --
// the session-best 246us version, re-confirmed R14). ONE WAVE per z. Lane t
// owns cols [16t,16t+16); at step s handles row-group g = s - t:
//   phi[r,c] = b[c] + q[r,c-1]*phi[r,c-1]        (1 fma)
//   b[c]     = fma(-q[r,c], phi[r,c], phi[r,c])  (= phi*p, 1 fma)
// Cross-lane: ONE batch of 8 __shfl_up(.,1) per step (phi15/q15 x 4 rows).
// q for step s+1 prefetched into registers (ping-pong pA/pB).
// Cross-lane = __shfl only (DPP failed 3x on gfx950 -- permanently banned).
// ---------------------------------------------------------------------------
__global__ __launch_bounds__(64) void mono_rec_k(float* __restrict__ P)
{
  const int z = blockIdx.x;
  float* __restrict__ Pz = P + ((size_t)z << 20);
  const int t = threadIdx.x;     // lane 0..63
  const int col0 = t << 4;       // first owned column

  float b[16];                   // carry: b[c] = phi[r-1,c] * p[r-1,c]
#pragma unroll
  for (int c = 0; c < 16; ++c) b[c] = 0.0f;
  float phi15h[4], q15h[4];      // col-15 values of the 4 rows, for lane t+1
#pragma unroll
  for (int k = 0; k < 4; ++k) { phi15h[k] = 0.0f; q15h[k] = 0.0f; }

  float pA[4][16], pB[4][16];    // q ping-pong (4 rows x 16 cols)

  // prologue: load slot 0 into pA
#pragma unroll
  for (int k = 0; k < 4; ++k) {
    const float* lp = Pz + (k << 10) + col0;
#pragma unroll
    for (int q = 0; q < 4; ++q)
      *(float4*)&pA[k][4 * q] = *(const float4*)(lp + 4 * q);
  }

  auto step = [&](int s, float (&pcur)[4][16], float (&pnext)[4][16]) {
    // boundary batch from lane t-1 first (latency overlaps prefetch issue).
    // Unconditional so source lanes are active in the shuffle.
    float phiL[4], qL[4];
#pragma unroll
    for (int k = 0; k < 4; ++k) {
      phiL[k] = __shfl_up(phi15h[k], 1);
      qL[k]   = __shfl_up(q15h[k], 1);
    }

    // prefetch next step's slot (never aliases in-flight stores: slots
    // s-1, s vs (s+1)&255 are distinct; wrap-overlap lanes are invalid)
    {
      const float* np = Pz + ((size_t)((s + 1) & 255) << 12) + col0;
#pragma unroll
      for (int k = 0; k < 4; ++k)
#pragma unroll
        for (int q = 0; q < 4; ++q)
          *(float4*)&pnext[k][4 * q] = *(const float4*)(np + (k << 10) + 4 * q);
    }

    const int g = s - t;
    if (g >= 0 && g < 256) {
      float* sp = Pz + ((size_t)(s & 255) << 12) + col0;
      float phi[16];
#pragma unroll
      for (int k = 0; k < 4; ++k) {
        const float* qk = pcur[k];
        if (g == 0 && k == 0) {
          // row 0: phi = onehot(col 0)
#pragma unroll
          for (int c = 0; c < 16; ++c) phi[c] = 0.0f;
          if (t == 0) phi[0] = 1.0f;
        } else {
          const float H0 = (t == 0) ? 0.0f : qL[k];
          float x = fmaf(H0, phiL[k], b[0]);
          phi[0] = x;
#pragma unroll
          for (int c = 1; c < 16; ++c) {
            x = fmaf(qk[c - 1], x, b[c]);
            phi[c] = x;
          }
        }
        // carry for next row (b = phi*p = phi - q*phi) + neighbor holds
#pragma unroll
        for (int c = 0; c < 16; ++c) b[c] = fmaf(-qk[c], phi[c], phi[c]);
        q15h[k]   = qk[15];
        phi15h[k] = phi[15];
        // write phi over q's cells (in-place, coalesced)
#pragma unroll
        for (int q = 0; q < 4; ++q)
          *(float4*)(sp + (k << 10) + 4 * q) = *(float4*)&phi[4 * q];
      }
    }
  };

  for (int s0 = 0; s0 < 320; s0 += 2) {
    step(s0, pA, pB);
    step(s0 + 1, pB, pA);
  }
}

// ---------------------------------------------------------------------------
extern "C" void kernel_launch(void* const* d_in, const int* in_sizes, int n_in,
                              void* d_out, int out_size, void* d_ws, size_t ws_size,
                              hipStream_t stream)
{
  const float* query = (const float*)d_in[0];
  const float* key   = (const float*)d_in[1];
  const float* value = (const float*)d_in[2];
  const float* ipw   = (const float*)d_in[3];   // (1536,1024)
  const float* ipb   = (const float*)d_in[4];   // (1536,)
  const float* opw   = (const float*)d_in[5];   // (1024,1024)
  const float* opb   = (const float*)d_in[6];   // (1024,)
  float* out = (float*)d_out;
  float* ws  = (float*)d_ws;

  float* XQ  = ws + OFF_XQ;
  float* XK  = ws + OFF_XK;
  float* XVt = ws + OFF_XVT;
  float* XO  = ws + OFF_XO;
  float* P   = ws + OFF_P;

  // fused in-projections: XQ + XK + XVt in one 768-block launch
  inproj_k<<<dim3(768), 256, 0, stream>>>(
      query, key, value, ipw, ipb, XQ, XK, XVt);

  // scores + sigmoid + clip -> q = 1-p (group-diagonal layout)
  scores_mfma_k<<<dim3(16, 16, 32), 256, 0, stream>>>(XQ, XK, P);

  // monotonic recurrence in place (R11 single-wave, session best)
  mono_rec_k<<<dim3(32), dim3(64), 0, stream>>>(P);

  // phi @ V -> XO (NT against transposed V; A read through diagonal map)
  pv_mfma_k<<<dim3(1, 16, 32), 256, 0, stream>>>(P, XVt, XO);

  // out-projection
  gemm_nt_mfma_k<<<dim3(16, 32), 256, 0, stream>>>(
      XO, 1024, opw, 1024, opb, out, 1024, 1024);
}